// Round 4
// baseline (10048.564 us; speedup 1.0000x reference)
//
#include <hip/hip_runtime.h>
#include <hip/hip_bf16.h>
#include <cstdint>

// ============================================================================
// 2-layer LSTM prefix + 59-step decode, persistent kernel, round 4.
// Round-4 changes (theory: round-3 is memory-side BW bound: 96 MB/step sc1
// h-broadcast + 26 MB/step L2-thrashing weight streams ~= 4.8 TB/s):
//   * Nt=64 tiles, 128 blocks x 1024 thr (16 waves), K split 4-way ACROSS
//     WAVE GROUPS inside the block, reduced via LDS -> aggregate h traffic
//     halves, weights become L2-resident (per-XCD footprint ~3.3 MB).
//   * h state is a RING of write-once slots (no address reuse): readers use
//     NORMAL CACHED loads (L2 broadcast!); writers still store sc1 so the
//     IF$ holds truth; first touch per XCD fetches from IF$. Correct by
//     construction (no line can be stale: address never read before write,
//     kernel-boundary flush cleans pre-existing state). Falls back to the
//     round-3 sc1-direct path if ws_size is too small (host-side branch).
// ============================================================================

typedef _Float16 half_t;
typedef _Float16 half8 __attribute__((ext_vector_type(8)));
typedef float float4v __attribute__((ext_vector_type(4)));
typedef int int32x4_t __attribute__((ext_vector_type(4)));
typedef float float32x4_t __attribute__((ext_vector_type(4)));

__device__ float32x4_t llvm_amdgcn_raw_buffer_load_fp32x4(
    int32x4_t srsrc, int voffset, int soffset, int aux)
    __asm("llvm.amdgcn.raw.buffer.load.v4f32");

#define AUX_SC1 16  // device scope: bypass L1/L2, served by IF$

union SrdU { int32x4_t v; struct { const void* p; unsigned nr, fl; } s; };
__device__ __forceinline__ int32x4_t make_srd(const void* p) {
  SrdU u; u.s.p = p; u.s.nr = 0xFFFFFFFFu; u.s.fl = 0x00020000u; return u.v;
}
__device__ __forceinline__ half8 bufld(int32x4_t srd, int voff) {
  union { float32x4_t f; half8 h; } u;
  u.f = llvm_amdgcn_raw_buffer_load_fp32x4(srd, voff, 0, AUX_SC1);
  return u.h;
}

__device__ __forceinline__ float sigm_(float x) { return 1.0f / (1.0f + __expf(-x)); }
__device__ __forceinline__ float tanh_(float x) {
  float ax = fabsf(x);
  float e = __expf(-2.0f * ax);
  float t = (1.0f - e) / (1.0f + e);
  return x < 0.0f ? -t : t;
}

// Relaxed device-scope barrier (no cache maintenance ops).
__device__ __forceinline__ void grid_barrier(int* cnt, int target) {
  asm volatile("" ::: "memory");
  __syncthreads();
  if (threadIdx.x == 0) {
    __hip_atomic_fetch_add(cnt, 1, __ATOMIC_RELAXED, __HIP_MEMORY_SCOPE_AGENT);
    while (__hip_atomic_load(cnt, __ATOMIC_RELAXED, __HIP_MEMORY_SCOPE_AGENT) < target) {
      __builtin_amdgcn_s_sleep(8);
    }
  }
  __syncthreads();
  asm volatile("" ::: "memory");
}

#define MFMA16(a, b, c) __builtin_amdgcn_mfma_f32_16x16x32_f16(a, b, c, 0, 0, 0)

// One [128 x 64] tile, K split over 4 wave-groups (kg = wave>>2), 4 waves per
// kgroup own 32 rows each (rg = wave&3). A = concat(A0,A1) fragment-linear
// [kblock][128][8]. W stream [kg][chunk][kb 8][col 64][8], chunk (64k) staged
// to LDS double-buffered. MODE 1 = ring (plain cached loads), 0 = sc1.
template <int MODE, bool A0PLAIN>
__device__ __forceinline__ void gemm4(
    const half_t* __restrict__ A0, const half_t* __restrict__ A1, int K0b,
    const half_t* __restrict__ Wst, int nch, int Kgb,
    char* smem, int tid, float4v acc[2][4]) {
  const int wv = tid >> 6, l = tid & 63;
  const int lrow = l & 15, lq = l >> 4;
  const int kg = wv >> 2, rg = wv & 3;
  const int r0 = rg * 32;
  half_t* ldsW = (half_t*)smem;

  int32x4_t srd0 = make_srd(A0);
  int32x4_t srd1 = make_srd(A1);

  const half_t* wsrc = Wst + kg * nch * 4096 + rg * 1024 + l * 8;
  half_t* wdst = ldsW + kg * 8192 + rg * 1024 + l * 8;

#define LDA4(d0, d1, kbb) { \
    const int kb_ = (kbb); \
    const bool u0_ = kb_ < K0b; \
    if (MODE == 1 || (A0PLAIN && u0_)) { \
      const half_t* p_ = (u0_ ? A0 + (long)kb_ * 1024 \
                              : A1 + (long)(kb_ - K0b) * 1024) + \
                         lq * 1024 + (r0 + lrow) * 8; \
      d0 = *(const half8*)p_; d1 = *(const half8*)(p_ + 128); \
    } else { \
      const int vo_ = (u0_ ? kb_ : kb_ - K0b) * 2048 + lq * 2048 + (r0 + lrow) * 16; \
      d0 = bufld(u0_ ? srd0 : srd1, vo_); \
      d1 = bufld(u0_ ? srd0 : srd1, vo_ + 256); \
    } }

  uint4 w0 = *(const uint4*)wsrc;
  uint4 w1 = *(const uint4*)(wsrc + 512);
  half8 a00, a01, a10, a11, n00, n01, n10, n11;
  LDA4(a00, a01, kg * Kgb);
  LDA4(a10, a11, kg * Kgb + 4);
  n00 = a00; n01 = a01; n10 = a10; n11 = a11;

  for (int c = 0; c < nch; ++c) {
    half_t* wd = wdst + (c & 1) * 4096;
    *(uint4*)wd = w0;
    *(uint4*)(wd + 512) = w1;
    __syncthreads();
    if (c + 1 < nch) {
      const half_t* ws2 = wsrc + (c + 1) * 4096;
      w0 = *(const uint4*)ws2;
      w1 = *(const uint4*)(ws2 + 512);
      LDA4(n00, n01, kg * Kgb + (c + 1) * 8);
      LDA4(n10, n11, kg * Kgb + (c + 1) * 8 + 4);
    }
    const half_t* bp = ldsW + kg * 8192 + (c & 1) * 4096 + lrow * 8;
#pragma unroll
    for (int ks = 0; ks < 2; ++ks) {
      const half8 af0 = ks ? a10 : a00;
      const half8 af1 = ks ? a11 : a01;
      const half_t* bpp = bp + (ks * 4 + lq) * 512;
#pragma unroll
      for (int nf = 0; nf < 4; ++nf) {
        half8 bf = *(const half8*)(bpp + nf * 128);
        acc[0][nf] = MFMA16(af0, bf, acc[0][nf]);
        acc[1][nf] = MFMA16(af1, bf, acc[1][nf]);
      }
    }
    a00 = n00; a01 = n01; a10 = n10; a11 = n11;
  }
  __syncthreads();  // LDS W region is about to be reused for reduction
#undef LDA4
}

// Cross-kgroup reduction via LDS (12 slots x 8 KB = 96 KB). kg0 waves end up
// holding the full [128 x 64] tile.
__device__ __forceinline__ void reduce_acc(float4v acc[2][4], char* smem, int tid) {
  const int wv = tid >> 6, l = tid & 63;
  const int kg = wv >> 2, rg = wv & 3;
  float* red = (float*)smem;
  if (kg > 0) {
    float* p = red + ((kg - 1) * 4 + rg) * 2048 + l * 4;
#pragma unroll
    for (int m = 0; m < 2; ++m)
#pragma unroll
      for (int nf = 0; nf < 4; ++nf)
        *(float4v*)(p + (m * 4 + nf) * 256) = acc[m][nf];
  }
  __syncthreads();
  if (kg == 0) {
#pragma unroll
    for (int g = 1; g < 4; ++g) {
      float* p = red + ((g - 1) * 4 + rg) * 2048 + l * 4;
#pragma unroll
      for (int m = 0; m < 2; ++m)
#pragma unroll
        for (int nf = 0; nf < 4; ++nf)
          acc[m][nf] += *(float4v*)(p + (m * 4 + nf) * 256);
    }
  }
}

// Cell epilogue (kg0 waves hold tile). cols = 16 units x 4 gates; gates of a
// unit live in a quad -> shfl_xor gather, lane q keeps row r==q. c private,
// h staged in LDS [kb 2][row 128][8] then stored device-scope (sc1).
__device__ __forceinline__ void epilogue_gates4(
    float4v acc[2][4], int tile, const float* __restrict__ biasArr,
    float* __restrict__ Cblk, char* smem, half_t* __restrict__ hDst, int tid) {
  const int wv = tid >> 6, l = tid & 63;
  const int kg = wv >> 2, rg = wv & 3;
  const int lrow = l & 15, lq = l >> 4, q = l & 3;
  half_t* hTile = (half_t*)(smem + 98304);
  if (kg == 0) {
#pragma unroll
    for (int m = 0; m < 2; ++m)
#pragma unroll
      for (int nf = 0; nf < 4; ++nf) {
        const float bias = biasArr[tile * 64 + nf * 16 + lrow];
        float gi = 0.f, gf = 0.f, gg = 0.f, go = 0.f;
#pragma unroll
        for (int r = 0; r < 4; ++r) {
          float x = acc[m][nf][r] + bias;
          float t1 = __shfl_xor(x, 1);
          float t2 = __shfl_xor(x, 2);
          float t3 = __shfl_xor(x, 3);
          if (r == q) {
            gi = (q == 0) ? x : (q == 1 ? t1 : (q == 2 ? t2 : t3));
            gf = (q == 1) ? x : (q == 0 ? t1 : (q == 3 ? t2 : t3));
            gg = (q == 2) ? x : (q == 3 ? t1 : (q == 0 ? t2 : t3));
            go = (q == 3) ? x : (q == 2 ? t1 : (q == 1 ? t2 : t3));
          }
        }
        const int row = rg * 32 + m * 16 + lq * 4 + q;
        const int ju = nf * 4 + (lrow >> 2);
        float iv = sigm_(gi), fv = sigm_(gf), gv = tanh_(gg), ov = sigm_(go);
        float cold = Cblk[row * 16 + ju];
        float cnew = fv * cold + iv * gv;
        float hnew = ov * tanh_(cnew);
        Cblk[row * 16 + ju] = cnew;
        hTile[(ju >> 3) * 1024 + row * 8 + (ju & 7)] = (half_t)hnew;
      }
  }
  __syncthreads();
  if (tid < 256) {
    const unsigned long long* src = (const unsigned long long*)(hTile + tid * 8);
    unsigned long long* dst = (unsigned long long*)(hDst + tile * 2048 + tid * 8);
    unsigned long long v0 = src[0], v1 = src[1];
    __hip_atomic_store(dst, v0, __ATOMIC_RELAXED, __HIP_MEMORY_SCOPE_AGENT);
    __hip_atomic_store(dst + 1, v1, __ATOMIC_RELAXED, __HIP_MEMORY_SCOPE_AGENT);
  }
}

__device__ __forceinline__ void epilogue_y4(
    float4v acc[2][4], int ty, int i, const float* __restrict__ biasY,
    float* __restrict__ out, int tid) {
  const int wv = tid >> 6, l = tid & 63;
  const int kg = wv >> 2, rg = wv & 3;
  const int lrow = l & 15, lq = l >> 4;
  if (kg != 0) return;
#pragma unroll
  for (int m = 0; m < 2; ++m)
#pragma unroll
    for (int nf = 0; nf < 4; ++nf) {
      const int d = ty * 64 + nf * 16 + lrow;
      const float bias = biasY[d];
#pragma unroll
      for (int r = 0; r < 4; ++r) {
        const int row = rg * 32 + m * 16 + lq * 4 + r;
        out[(long)row * 15360 + i * 256 + d] = acc[m][nf][r] + bias;
      }
    }
}

#define ZACC4 float4v acc[2][4]; { float4v z = {0.f, 0.f, 0.f, 0.f}; \
  acc[0][0]=z; acc[0][1]=z; acc[0][2]=z; acc[0][3]=z; \
  acc[1][0]=z; acc[1][1]=z; acc[1][2]=z; acc[1][3]=z; }

template <int MODE>
__global__ void __launch_bounds__(1024) k_lstm(
    const half_t* __restrict__ S0, const half_t* __restrict__ S1,
    const half_t* __restrict__ SD, const half_t* __restrict__ SY,
    const half_t* __restrict__ XH,
    half_t* __restrict__ H0, half_t* __restrict__ H1,
    float* __restrict__ C0, float* __restrict__ C1,
    const float* __restrict__ B0P, const float* __restrict__ B1P,
    const float* __restrict__ BD0P, float* __restrict__ out, int* cnt) {
  __shared__ char smem[102400];  // 64KB W stage | 96KB reduce (alias) + 4KB hTile
  const int w = blockIdx.x, tid = threadIdx.x;
#define HSLOT(base, idx) ((base) + (long)(MODE ? (idx) : ((idx) & 1)) * 131072)
  for (int s = 0; s < 376; ++s) {
    if (s <= 256) {  // prefix: L0@t=s (blocks 0-63) || L1@t=s-1 (blocks 64-127)
      if (w < 64) {
        if (s <= 255) {
          ZACC4;
          gemm4<MODE, true>(XH + (long)s * 32768, HSLOT(H0, s), 32,
                            S0 + (long)w * 81920, 5, 40, smem, tid, acc);
          reduce_acc(acc, smem, tid);
          epilogue_gates4(acc, w, B0P, C0 + w * 2048, smem, HSLOT(H0, s + 1), tid);
        }
      } else {
        if (s >= 1) {
          ZACC4;
          const int bw = w - 64;
          gemm4<MODE, false>(HSLOT(H0, s), HSLOT(H1, s - 1), 128,
                             S1 + (long)bw * 131072, 8, 64, smem, tid, acc);
          reduce_acc(acc, smem, tid);
          epilogue_gates4(acc, bw, B1P, C1 + bw * 2048, smem, HSLOT(H1, s), tid);
        }
      }
    } else if (s < 375) {  // decode
      const int d = s - 257, i = d >> 1;
      if ((d & 1) == 0) {  // cell0 (Weff-fused) on 0-63, y on 64-67
        if (w < 64) {
          ZACC4;
          gemm4<MODE, false>(HSLOT(H1, 256 + i), HSLOT(H0, 256 + i), 128,
                             SD + (long)w * 131072, 8, 64, smem, tid, acc);
          reduce_acc(acc, smem, tid);
          epilogue_gates4(acc, w, BD0P, C0 + w * 2048, smem, HSLOT(H0, 257 + i), tid);
        } else if (w < 68) {
          ZACC4;
          const int ty = w - 64;
          gemm4<MODE, false>(HSLOT(H1, 256 + i), HSLOT(H1, 256 + i), 128,
                             SY + (long)ty * 65536, 4, 32, smem, tid, acc);
          reduce_acc(acc, smem, tid);
          epilogue_y4(acc, ty, i, BD0P + 4096, out, tid);
        }
      } else {  // cell1 on blocks 64-127 (they own C1 from the prefix)
        if (w >= 64) {
          ZACC4;
          const int bw = w - 64;
          gemm4<MODE, false>(HSLOT(H0, 257 + i), HSLOT(H1, 256 + i), 128,
                             S1 + (long)bw * 131072, 8, 64, smem, tid, acc);
          reduce_acc(acc, smem, tid);
          epilogue_gates4(acc, bw, B1P, C1 + bw * 2048, smem, HSLOT(H1, 257 + i), tid);
        }
      }
    } else {  // s == 375: final y (step 59)
      if (w >= 64 && w < 68) {
        ZACC4;
        const int ty = w - 64;
        gemm4<MODE, false>(HSLOT(H1, 315), HSLOT(H1, 315), 128,
                           SY + (long)ty * 65536, 4, 32, smem, tid, acc);
        reduce_acc(acc, smem, tid);
        epilogue_y4(acc, ty, 59, BD0P + 4096, out, tid);
      }
    }
    grid_barrier(cnt, (s + 1) * 128);
  }
#undef HSLOT
}

// ======================= setup kernels =======================

// x[B,T,D] fp32 -> XH[t][kblock][row][8] fp16
__global__ void k_cvt_x(const float* __restrict__ x, half_t* __restrict__ XH) {
  int idx = blockIdx.x * 256 + threadIdx.x;  // 1,048,576 total
  int t = idx >> 12;
  int kb = (idx >> 7) & 31;
  int r = idx & 127;
  const float* src = x + ((long)((r << 8) + t)) * 256 + kb * 8;
  float4 v0 = *(const float4*)src;
  float4 v1 = *(const float4*)(src + 4);
  half_t tmp[8] = {(half_t)v0.x, (half_t)v0.y, (half_t)v0.z, (half_t)v0.w,
                   (half_t)v1.x, (half_t)v1.y, (half_t)v1.z, (half_t)v1.w};
  *(uint4*)(XH + (long)t * 32768 + kb * 1024 + r * 8) = *(const uint4*)tmp;
}

// Pack gate weights (row' = 4*unit + gate) into [tile 64][kg 4][c nch]
// [kb 8][col 64][8] streams. k = kg*Kg + c*64 + kb*8; source A (stride KA)
// if k < KA else Bsrc (stride 1024). skipA: leave k<KA region untouched.
__global__ void k_pack_gates(const float* __restrict__ A, int KA,
                             const float* __restrict__ Bsrc,
                             half_t* __restrict__ dst, int nch, int skipA) {
  int idx = blockIdx.x * 256 + threadIdx.x;
  int nn = idx & 63;
  int kb = (idx >> 6) & 7;
  int t2 = idx >> 9;
  int c = t2 % nch;
  int t3 = t2 / nch;
  int kg = t3 & 3;
  int tile = t3 >> 2;
  if (tile >= 64) return;
  int Kg = nch * 64;
  int k = kg * Kg + c * 64 + kb * 8;
  int rp = tile * 64 + nn;
  int r = ((rp & 3) << 10) + (rp >> 2);
  const float* src;
  if (k < KA) {
    if (skipA) return;
    src = A + (long)r * KA + k;
  } else {
    src = Bsrc + (long)r * 1024 + (k - KA);
  }
  float4 v0 = *(const float4*)src;
  float4 v1 = *(const float4*)(src + 4);
  half_t tmp[8] = {(half_t)v0.x, (half_t)v0.y, (half_t)v0.z, (half_t)v0.w,
                   (half_t)v1.x, (half_t)v1.y, (half_t)v1.z, (half_t)v1.w};
  *(uint4*)(dst + (long)tile * (4L * Kg * 64) + (long)kg * (nch * 4096) +
            c * 4096 + kb * 512 + nn * 8) = *(const uint4*)tmp;
}

// W_lin rows (no permutation) -> SY [tile 4][kg 4][c 4][kb 8][col 64][8]
__global__ void k_pack_y(const float* __restrict__ Wlin,
                         half_t* __restrict__ SY) {
  int idx = blockIdx.x * 256 + threadIdx.x;  // 32768 total
  int nn = idx & 63;
  int kb = (idx >> 6) & 7;
  int c = (idx >> 9) & 3;
  int kg = (idx >> 11) & 3;
  int tile = idx >> 13;
  int d = tile * 64 + nn;
  int k = kg * 256 + c * 64 + kb * 8;
  const float* src = Wlin + (long)d * 1024 + k;
  float4 v0 = *(const float4*)src;
  float4 v1 = *(const float4*)(src + 4);
  half_t tmp[8] = {(half_t)v0.x, (half_t)v0.y, (half_t)v0.z, (half_t)v0.w,
                   (half_t)v1.x, (half_t)v1.y, (half_t)v1.z, (half_t)v1.w};
  *(uint4*)(SY + (long)tile * 65536 + kg * 16384 + c * 4096 + kb * 512 + nn * 8) =
      *(const uint4*)tmp;
}

__global__ void k_bias_simple(const float* bi0, const float* bh0,
                              const float* bi1, const float* bh1,
                              const float* blin, float* b0p, float* b1p,
                              float* bD0p) {
  int rp = blockIdx.x * blockDim.x + threadIdx.x;
  if (rp < 4096) {
    int r = ((rp & 3) << 10) + (rp >> 2);
    b0p[rp] = bi0[r] + bh0[r];
    b1p[rp] = bi1[r] + bh1[r];
  } else if (rp < 4352) {
    bD0p[rp] = blin[rp - 4096];
  }
}

// biasD0p[row'] = b_ih0[r] + b_hh0[r] + dot(W_ih0[r,:], b_lin)
__global__ void k_bias_dot(const float* __restrict__ Wih0,
                           const float* __restrict__ blin,
                           const float* __restrict__ bi0,
                           const float* __restrict__ bh0,
                           float* __restrict__ bD0p) {
  int wv = threadIdx.x >> 6, l = threadIdx.x & 63;
  int r = blockIdx.x * 4 + wv;
  float s = 0.f;
#pragma unroll
  for (int c = 0; c < 4; ++c) s += Wih0[r * 256 + c * 64 + l] * blin[c * 64 + l];
#pragma unroll
  for (int o = 32; o >= 1; o >>= 1) s += __shfl_xor(s, o);
  if (l == 0) {
    int rp = ((r & 1023) << 2) | (r >> 10);
    bD0p[rp] = bi0[r] + bh0[r] + s;
  }
}

// Weff = W_ih0(4096x256) @ W_lin(256x1024) fp32 -> fp16 into SD (k<1024).
__global__ void k_weff(const float* __restrict__ Wih0,
                       const float* __restrict__ Wlin,
                       half_t* __restrict__ SD) {
  __shared__ float At[64][65];
  __shared__ float Bt[64][65];
  const int rt = blockIdx.x, jt = blockIdx.y;
  const int tid = threadIdx.x;
  const int tx = tid & 15, ty = tid >> 4;
  float acc[4][4] = {};
  for (int k0 = 0; k0 < 256; k0 += 64) {
    __syncthreads();
#pragma unroll
    for (int i = 0; i < 16; ++i) {
      int lin = tid + 256 * i;
      int rr = lin >> 6, kk = lin & 63;
      At[rr][kk] = Wih0[(rt * 64 + rr) * 256 + k0 + kk];
      Bt[rr][kk] = Wlin[(k0 + rr) * 1024 + jt * 64 + kk];
    }
    __syncthreads();
    for (int kk = 0; kk < 64; ++kk) {
      float a[4], b[4];
#pragma unroll
      for (int i = 0; i < 4; ++i) a[i] = At[ty * 4 + i][kk];
#pragma unroll
      for (int i = 0; i < 4; ++i) b[i] = Bt[kk][tx * 4 + i];
#pragma unroll
      for (int i = 0; i < 4; ++i)
#pragma unroll
        for (int jx = 0; jx < 4; ++jx) acc[i][jx] += a[i] * b[jx];
    }
  }
#pragma unroll
  for (int i = 0; i < 4; ++i) {
    int r = rt * 64 + ty * 4 + i;
    int rp = ((r & 1023) << 2) | (r >> 10);
    int tile = rp >> 6, nn = rp & 63;
#pragma unroll
    for (int jx = 0; jx < 4; ++jx) {
      int j = jt * 64 + tx * 4 + jx;
      SD[(long)tile * 131072 + (j >> 9) * 32768 + ((j >> 6) & 7) * 4096 +
         ((j >> 3) & 7) * 512 + nn * 8 + (j & 7)] = (half_t)acc[i][jx];
    }
  }
}

// ======================= launch =======================

extern "C" void kernel_launch(void* const* d_in, const int* in_sizes, int n_in,
                              void* d_out, int out_size, void* d_ws, size_t ws_size,
                              hipStream_t stream) {
  (void)in_sizes; (void)n_in; (void)out_size;
  const float* x    = (const float*)d_in[0];
  const float* Wih0 = (const float*)d_in[1];
  const float* Whh0 = (const float*)d_in[2];
  const float* bi0  = (const float*)d_in[3];
  const float* bh0  = (const float*)d_in[4];
  const float* Wih1 = (const float*)d_in[5];
  const float* Whh1 = (const float*)d_in[6];
  const float* bi1  = (const float*)d_in[7];
  const float* bh1  = (const float*)d_in[8];
  const float* Wlin = (const float*)d_in[9];
  const float* blin = (const float*)d_in[10];
  float* out = (float*)d_out;
  char* ws = (char*)d_ws;

  half_t* S0  = (half_t*)(ws + 0);         // 64 x 1280x64x2 = 10 MB
  half_t* S1  = (half_t*)(ws + 10485760);  // 64 x 2048x64x2 = 16 MB
  half_t* SD  = (half_t*)(ws + 27262976);  // 16 MB
  half_t* SY  = (half_t*)(ws + 44040192);  // 512 KB
  half_t* XH  = (half_t*)(ws + 44564480);  // 16 MB
  float*  C0  = (float*)(ws + 61341696);   // 512 KB [tile][row 128][16]
  float*  C1  = (float*)(ws + 61865984);
  float*  B0P = (float*)(ws + 62390272);
  float*  B1P = (float*)(ws + 62406656);
  float*  BD0P= (float*)(ws + 62423040);   // 17408 B (4352 floats)
  int*    CNT = (int*)(ws + 62440448);     // 256 B
  const size_t FIXED = 62440704;
  const size_t SLOT  = 262144;             // one h slot: 128x1024 fp16
  const size_t RING  = 320 * SLOT;         // 83,886,080
  const bool ring = ws_size >= FIXED + 2 * RING;  // ~230 MB
  const size_t hsz = ring ? RING : 2 * SLOT;
  half_t* H0 = (half_t*)(ws + FIXED);
  half_t* H1 = (half_t*)(ws + FIXED + hsz);

  // zero c-state, biases, barrier counter; zero h slot 0 of each ring
  hipMemsetAsync(ws + 61341696, 0, 1099008, stream);
  hipMemsetAsync(H0, 0, SLOT, stream);
  hipMemsetAsync(H1, 0, SLOT, stream);

  k_cvt_x<<<4096, 256, 0, stream>>>(x, XH);
  k_bias_simple<<<17, 256, 0, stream>>>(bi0, bh0, bi1, bh1, blin, B0P, B1P, BD0P);
  k_bias_dot<<<1024, 256, 0, stream>>>(Wih0, blin, bi0, bh0, BD0P);
  k_pack_gates<<<2560, 256, 0, stream>>>(Wih0, 256, Whh0, S0, 5, 0);
  k_pack_gates<<<4096, 256, 0, stream>>>(Wih1, 1024, Whh1, S1, 8, 0);
  k_pack_gates<<<4096, 256, 0, stream>>>(nullptr, 1024, Whh0, SD, 8, 1);
  k_pack_y<<<128, 256, 0, stream>>>(Wlin, SY);
  k_weff<<<dim3(64, 16), 256, 0, stream>>>(Wih0, Wlin, SD);

  if (ring) {
    k_lstm<1><<<128, 1024, 0, stream>>>(S0, S1, SD, SY, XH, H0, H1, C0, C1,
                                        B0P, B1P, BD0P, out, CNT);
  } else {
    k_lstm<0><<<128, 1024, 0, stream>>>(S0, S1, SD, SY, XH, H0, H1, C0, C1,
                                        B0P, B1P, BD0P, out, CNT);
  }
}

// Round 5
// 9182.624 us; speedup vs baseline: 1.0943x; 1.0943x over previous
//
#include <hip/hip_runtime.h>
#include <hip/hip_bf16.h>
#include <cstdint>

// ============================================================================
// 2-layer LSTM prefix + 59-step decode, persistent kernel, round 5.
// Theory: rounds 3/4 were both limited by re-reading ~24 MB/step of weights
// from the memory system (IF$ broadcast or L2 thrash, both ~26 us/step).
// Round 5: WEIGHTS LIVE IN LDS for the whole kernel.
//   * 256 blocks x 256 thr, 1 block/CU (LDS-bound), each owns a 32-col tile.
//   * W tile (80/128 KB) loaded to LDS once; SD swapped in at idle s==256.
//   * K-loop: A-frags from global (plain cached; h = write-once ring slots,
//     sc1 stores -> IF$ truth), B-frags ds_read_b128, NO syncthreads.
//   * c-state entirely in 4 VGPRs per lane (no global c traffic).
//   * Layout [kk][lq4][col32][8]: ds phases are 2-way-conflict (free).
// ============================================================================

typedef _Float16 half_t;
typedef _Float16 half8 __attribute__((ext_vector_type(8)));
typedef float float4v __attribute__((ext_vector_type(4)));

__device__ __forceinline__ float sigm_(float x) { return 1.0f / (1.0f + __expf(-x)); }
__device__ __forceinline__ float tanh_(float x) {
  float ax = fabsf(x);
  float e = __expf(-2.0f * ax);
  float t = (1.0f - e) / (1.0f + e);
  return x < 0.0f ? -t : t;
}

// Relaxed device-scope barrier (no cache maintenance ops).
__device__ __forceinline__ void grid_barrier(int* cnt, int target) {
  asm volatile("" ::: "memory");
  __syncthreads();
  if (threadIdx.x == 0) {
    __hip_atomic_fetch_add(cnt, 1, __ATOMIC_RELAXED, __HIP_MEMORY_SCOPE_AGENT);
    while (__hip_atomic_load(cnt, __ATOMIC_RELAXED, __HIP_MEMORY_SCOPE_AGENT) < target) {
      __builtin_amdgcn_s_sleep(8);
    }
  }
  __syncthreads();
  asm volatile("" ::: "memory");
}

#define MFMA16(a, b, c) __builtin_amdgcn_mfma_f32_16x16x32_f16(a, b, c, 0, 0, 0)

// [128 x 32] tile GEMM. A = concat(A0,A1), fragment-linear [kb][row 128][8],
// K0B kb-blocks from A0. B-frags from LDS-resident W [kk][lq 4][col 32][8].
// Wave rg owns rows [32rg, 32rg+32). No barriers inside.
template <int KT32, int K0B>
__device__ __forceinline__ void gemm_l(
    const half_t* __restrict__ A0, const half_t* __restrict__ A1,
    const half_t* ldsW, int tid, float4v acc[2][2]) {
  const int l = tid & 63, rg = tid >> 6;
  const int lrow = l & 15, lq = l >> 4;
  const int ro = (rg * 32 + lrow) * 8 + lq * 1024;
#pragma unroll
  for (int kk = 0; kk < KT32; ++kk) {
    const int kb = kk * 4;
    const half_t* ap =
        (kb < K0B ? A0 + (long)kb * 1024 : A1 + (long)(kb - K0B) * 1024) + ro;
    half8 a0 = *(const half8*)ap;
    half8 a1 = *(const half8*)(ap + 128);
    const half_t* bp = ldsW + kk * 1024 + lq * 256 + lrow * 8;
    half8 b0 = *(const half8*)bp;
    half8 b1 = *(const half8*)(bp + 128);
    acc[0][0] = MFMA16(a0, b0, acc[0][0]);
    acc[0][1] = MFMA16(a0, b1, acc[0][1]);
    acc[1][0] = MFMA16(a1, b0, acc[1][0]);
    acc[1][1] = MFMA16(a1, b1, acc[1][1]);
  }
}

// Same but B-frags streamed from global (for the small y-GEMM).
template <int KT32>
__device__ __forceinline__ void gemm_g(
    const half_t* __restrict__ A0, const half_t* __restrict__ Wg,
    int tid, float4v acc[2][2]) {
  const int l = tid & 63, rg = tid >> 6;
  const int lrow = l & 15, lq = l >> 4;
  const int ro = (rg * 32 + lrow) * 8 + lq * 1024;
#pragma unroll
  for (int kk = 0; kk < KT32; ++kk) {
    const half_t* ap = A0 + (long)kk * 4096 + ro;
    half8 a0 = *(const half8*)ap;
    half8 a1 = *(const half8*)(ap + 128);
    const half_t* bp = Wg + kk * 1024 + lq * 256 + lrow * 8;
    half8 b0 = *(const half8*)bp;
    half8 b1 = *(const half8*)(bp + 128);
    acc[0][0] = MFMA16(a0, b0, acc[0][0]);
    acc[0][1] = MFMA16(a0, b1, acc[0][1]);
    acc[1][0] = MFMA16(a1, b0, acc[1][0]);
    acc[1][1] = MFMA16(a1, b1, acc[1][1]);
  }
}

// Cell epilogue for a [128 x 32] gate tile (8 units x 4 gates per col group).
// D layout: col = lane&15, row = (lane>>4)*4 + reg; unit gates live in a
// quad -> shfl_xor gather, lane q keeps row r==q. c persists in 4 VGPRs.
// h staged via 2 KB LDS tile, stored device-scope (sc1) to the ring slot.
__device__ __forceinline__ void epi_gates(
    float4v acc[2][2], int tile, const float* __restrict__ biasArr,
    float c[2][2], half_t* hTile, half_t* __restrict__ hDst, int tid) {
  const int l = tid & 63, rg = tid >> 6;
  const int lrow = l & 15, lq = l >> 4, q = l & 3, a = lrow >> 2;
#pragma unroll
  for (int m = 0; m < 2; ++m)
#pragma unroll
    for (int nf = 0; nf < 2; ++nf) {
      const float bias = biasArr[tile * 32 + nf * 16 + lrow];
      float gi = 0.f, gf = 0.f, gg = 0.f, go = 0.f;
#pragma unroll
      for (int r = 0; r < 4; ++r) {
        float x = acc[m][nf][r] + bias;
        float t1 = __shfl_xor(x, 1);
        float t2 = __shfl_xor(x, 2);
        float t3 = __shfl_xor(x, 3);
        if (r == q) {
          gi = (q == 0) ? x : (q == 1 ? t1 : (q == 2 ? t2 : t3));
          gf = (q == 1) ? x : (q == 0 ? t1 : (q == 3 ? t2 : t3));
          gg = (q == 2) ? x : (q == 3 ? t1 : (q == 0 ? t2 : t3));
          go = (q == 3) ? x : (q == 2 ? t1 : (q == 1 ? t2 : t3));
        }
      }
      const int row = rg * 32 + m * 16 + lq * 4 + q;
      const int ju = nf * 4 + a;
      float iv = sigm_(gi), fv = sigm_(gf), gv = tanh_(gg), ov = sigm_(go);
      float cnew = fv * c[m][nf] + iv * gv;
      c[m][nf] = cnew;
      hTile[row * 8 + ju] = (half_t)(ov * tanh_(cnew));
    }
  __syncthreads();
  if (tid < 128) {
    const unsigned long long* s = (const unsigned long long*)(hTile + tid * 8);
    unsigned long long v0 = s[0], v1 = s[1];
    unsigned long long* d = (unsigned long long*)(hDst + tid * 8);
    __hip_atomic_store(d, v0, __ATOMIC_RELAXED, __HIP_MEMORY_SCOPE_AGENT);
    __hip_atomic_store(d + 1, v1, __ATOMIC_RELAXED, __HIP_MEMORY_SCOPE_AGENT);
  }
}

__device__ __forceinline__ void epi_y(
    float4v acc[2][2], int ytile, int i, const float* __restrict__ biasY,
    float* __restrict__ out, int tid) {
  const int l = tid & 63, rg = tid >> 6;
  const int lrow = l & 15, lq = l >> 4;
#pragma unroll
  for (int m = 0; m < 2; ++m)
#pragma unroll
    for (int nf = 0; nf < 2; ++nf) {
      const int d = ytile * 32 + nf * 16 + lrow;
      const float b = biasY[d];
#pragma unroll
      for (int r = 0; r < 4; ++r) {
        const int row = rg * 32 + m * 16 + lq * 4 + r;
        out[(long)row * 15360 + i * 256 + d] = acc[m][nf][r] + b;
      }
    }
}

__device__ __forceinline__ void loadW(const half_t* __restrict__ src,
                                      half_t* dst, int halves, int tid) {
  for (int i = tid * 8; i < halves; i += 2048)
    *(uint4*)(dst + i) = *(const uint4*)(src + i);
}

#define ZACC2 float4v acc[2][2]; { float4v z = {0.f, 0.f, 0.f, 0.f}; \
  acc[0][0] = z; acc[0][1] = z; acc[1][0] = z; acc[1][1] = z; }

__global__ void __launch_bounds__(256, 1) k_lstm(
    const half_t* __restrict__ S0, const half_t* __restrict__ S1,
    const half_t* __restrict__ SD, const half_t* __restrict__ SY,
    const half_t* __restrict__ XH,
    half_t* __restrict__ H0, half_t* __restrict__ H1,
    const float* __restrict__ B0P, const float* __restrict__ B1P,
    const float* __restrict__ BD0P, float* __restrict__ out, int* cnt) {
  __shared__ char smem[133120];  // 128 KB W (persistent) + 2 KB hTile
  half_t* ldsW = (half_t*)smem;
  half_t* hTile = (half_t*)(smem + 131072);
  const int w = blockIdx.x, tid = threadIdx.x;
  float c[2][2] = {{0.f, 0.f}, {0.f, 0.f}};

  // one-time W -> LDS (block-local; no grid sync needed)
  if (w < 128) loadW(S0 + (long)w * 40960, ldsW, 40960, tid);
  else         loadW(S1 + (long)(w - 128) * 65536, ldsW, 65536, tid);
  __syncthreads();

#define SLOTP(base, idx) ((base) + (long)(idx) * 131072)
  for (int s = 0; s < 376; ++s) {
    if (s <= 256) {  // prefix: L0@t=s (blocks 0-127) || L1@t=s-1 (128-255)
      if (w < 128) {
        if (s <= 255) {
          ZACC2;
          gemm_l<40, 32>(XH + (long)s * 32768, SLOTP(H0, s), ldsW, tid, acc);
          epi_gates(acc, w, B0P, c, hTile, SLOTP(H0, s + 1) + w * 1024, tid);
        } else {
          // idle phase: swap in decode cell0 weights (Weff|Whh0)
          loadW(SD + (long)w * 65536, ldsW, 65536, tid);
        }
      } else if (s >= 1) {
        ZACC2;
        gemm_l<64, 128>(SLOTP(H0, s), SLOTP(H1, s - 1), ldsW, tid, acc);
        epi_gates(acc, w - 128, B1P, c, hTile,
                  SLOTP(H1, s) + (w - 128) * 1024, tid);
      }
    } else if (s < 375) {  // decode
      const int d = s - 257, i = d >> 1;
      if ((d & 1) == 0) {  // cell0 (Weff-fused) on 0-127; y on 248-255
        if (w < 128) {
          ZACC2;
          gemm_l<64, 128>(SLOTP(H1, 256 + i), SLOTP(H0, 256 + i), ldsW, tid, acc);
          epi_gates(acc, w, BD0P, c, hTile, SLOTP(H0, 257 + i) + w * 1024, tid);
        } else if (w >= 248) {
          ZACC2;
          gemm_g<32>(SLOTP(H1, 256 + i), SY + (long)(w - 248) * 32768, tid, acc);
          epi_y(acc, w - 248, i, BD0P + 4096, out, tid);
        }
      } else {  // cell1 on blocks 128-255 (S1 still LDS-resident)
        if (w >= 128) {
          ZACC2;
          gemm_l<64, 128>(SLOTP(H0, 257 + i), SLOTP(H1, 256 + i), ldsW, tid, acc);
          epi_gates(acc, w - 128, B1P, c, hTile,
                    SLOTP(H1, 257 + i) + (w - 128) * 1024, tid);
        }
      }
    } else {  // s == 375: final y (step 59)
      if (w >= 248) {
        ZACC2;
        gemm_g<32>(SLOTP(H1, 315), SY + (long)(w - 248) * 32768, tid, acc);
        epi_y(acc, w - 248, 59, BD0P + 4096, out, tid);
      }
    }
    grid_barrier(cnt, (s + 1) * 256);
  }
#undef SLOTP
}

// ======================= setup kernels =======================

// x[B,T,D] fp32 -> XH[t][kb 32][row 128][8] fp16
__global__ void k_cvt_x(const float* __restrict__ x, half_t* __restrict__ XH) {
  int idx = blockIdx.x * 256 + threadIdx.x;  // 1,048,576 total
  int t = idx >> 12;
  int kb = (idx >> 7) & 31;
  int r = idx & 127;
  const float* src = x + ((long)((r << 8) + t)) * 256 + kb * 8;
  float4 v0 = *(const float4*)src;
  float4 v1 = *(const float4*)(src + 4);
  half_t tmp[8] = {(half_t)v0.x, (half_t)v0.y, (half_t)v0.z, (half_t)v0.w,
                   (half_t)v1.x, (half_t)v1.y, (half_t)v1.z, (half_t)v1.w};
  *(uint4*)(XH + (long)t * 32768 + kb * 1024 + r * 8) = *(const uint4*)tmp;
}

// Gate weights (row' = 4*unit + gate) -> [tile 128][kk KT32][lq 4][col 32][8].
// k = kk*32 + lq*8; src A (stride KA) if k < KA else Bsrc (stride 1024).
__global__ void k_pack32(const float* __restrict__ A, int KA,
                         const float* __restrict__ Bsrc,
                         half_t* __restrict__ dst, int KT32, int skipA) {
  int idx = blockIdx.x * 256 + threadIdx.x;
  int nn = idx & 31;
  int lq = (idx >> 5) & 3;
  int t2 = idx >> 7;
  int kk = t2 % KT32;
  int tile = t2 / KT32;
  if (tile >= 128) return;
  int k = kk * 32 + lq * 8;
  int rp = tile * 32 + nn;
  int r = ((rp & 3) << 10) + (rp >> 2);
  const float* src;
  if (k < KA) {
    if (skipA) return;
    src = A + (long)r * KA + k;
  } else {
    src = Bsrc + (long)r * 1024 + (k - KA);
  }
  float4 v0 = *(const float4*)src;
  float4 v1 = *(const float4*)(src + 4);
  half_t tmp[8] = {(half_t)v0.x, (half_t)v0.y, (half_t)v0.z, (half_t)v0.w,
                   (half_t)v1.x, (half_t)v1.y, (half_t)v1.z, (half_t)v1.w};
  *(uint4*)(dst + (long)tile * (KT32 * 1024) + kk * 1024 + lq * 256 + nn * 8) =
      *(const uint4*)tmp;
}

// W_lin rows (no permutation) -> SY [tile 8][kk 32][lq 4][col 32][8]
__global__ void k_pack_y32(const float* __restrict__ Wlin,
                           half_t* __restrict__ SY) {
  int idx = blockIdx.x * 256 + threadIdx.x;  // 32768 total
  int nn = idx & 31;
  int lq = (idx >> 5) & 3;
  int kk = (idx >> 7) & 31;
  int tile = idx >> 12;
  int d = tile * 32 + nn;
  int k = kk * 32 + lq * 8;
  const float* src = Wlin + (long)d * 1024 + k;
  float4 v0 = *(const float4*)src;
  float4 v1 = *(const float4*)(src + 4);
  half_t tmp[8] = {(half_t)v0.x, (half_t)v0.y, (half_t)v0.z, (half_t)v0.w,
                   (half_t)v1.x, (half_t)v1.y, (half_t)v1.z, (half_t)v1.w};
  *(uint4*)(SY + (long)tile * 32768 + kk * 1024 + lq * 256 + nn * 8) =
      *(const uint4*)tmp;
}

__global__ void k_bias_simple(const float* bi0, const float* bh0,
                              const float* bi1, const float* bh1,
                              const float* blin, float* b0p, float* b1p,
                              float* bD0p) {
  int rp = blockIdx.x * blockDim.x + threadIdx.x;
  if (rp < 4096) {
    int r = ((rp & 3) << 10) + (rp >> 2);
    b0p[rp] = bi0[r] + bh0[r];
    b1p[rp] = bi1[r] + bh1[r];
  } else if (rp < 4352) {
    bD0p[rp] = blin[rp - 4096];
  }
}

// biasD0p[row'] = b_ih0[r] + b_hh0[r] + dot(W_ih0[r,:], b_lin)
__global__ void k_bias_dot(const float* __restrict__ Wih0,
                           const float* __restrict__ blin,
                           const float* __restrict__ bi0,
                           const float* __restrict__ bh0,
                           float* __restrict__ bD0p) {
  int wv = threadIdx.x >> 6, l = threadIdx.x & 63;
  int r = blockIdx.x * 4 + wv;
  float s = 0.f;
#pragma unroll
  for (int c = 0; c < 4; ++c) s += Wih0[r * 256 + c * 64 + l] * blin[c * 64 + l];
#pragma unroll
  for (int o = 32; o >= 1; o >>= 1) s += __shfl_xor(s, o);
  if (l == 0) {
    int rp = ((r & 1023) << 2) | (r >> 10);
    bD0p[rp] = bi0[r] + bh0[r] + s;
  }
}

// Weff = W_ih0(4096x256) @ W_lin(256x1024) fp32 -> fp16 into SD (k < 1024).
__global__ void k_weff(const float* __restrict__ Wih0,
                       const float* __restrict__ Wlin,
                       half_t* __restrict__ SD) {
  __shared__ float At[64][65];
  __shared__ float Bt[64][65];
  const int rt = blockIdx.x, jt = blockIdx.y;
  const int tid = threadIdx.x;
  const int tx = tid & 15, ty = tid >> 4;
  float acc[4][4] = {};
  for (int k0 = 0; k0 < 256; k0 += 64) {
    __syncthreads();
#pragma unroll
    for (int i = 0; i < 16; ++i) {
      int lin = tid + 256 * i;
      int rr = lin >> 6, kk = lin & 63;
      At[rr][kk] = Wih0[(rt * 64 + rr) * 256 + k0 + kk];
      Bt[rr][kk] = Wlin[(k0 + rr) * 1024 + jt * 64 + kk];
    }
    __syncthreads();
    for (int kk = 0; kk < 64; ++kk) {
      float a[4], b[4];
#pragma unroll
      for (int i = 0; i < 4; ++i) a[i] = At[ty * 4 + i][kk];
#pragma unroll
      for (int i = 0; i < 4; ++i) b[i] = Bt[kk][tx * 4 + i];
#pragma unroll
      for (int i = 0; i < 4; ++i)
#pragma unroll
        for (int jx = 0; jx < 4; ++jx) acc[i][jx] += a[i] * b[jx];
    }
  }
#pragma unroll
  for (int i = 0; i < 4; ++i) {
    int r = rt * 64 + ty * 4 + i;
    int rp = ((r & 1023) << 2) | (r >> 10);
    int tile = rp >> 5, nn = rp & 31;
#pragma unroll
    for (int jx = 0; jx < 4; ++jx) {
      int j = jt * 64 + tx * 4 + jx;
      SD[(long)tile * 65536 + (j >> 5) * 1024 + ((j >> 3) & 3) * 256 + nn * 8 +
         (j & 7)] = (half_t)acc[i][jx];
    }
  }
}

// ======================= launch =======================

extern "C" void kernel_launch(void* const* d_in, const int* in_sizes, int n_in,
                              void* d_out, int out_size, void* d_ws, size_t ws_size,
                              hipStream_t stream) {
  (void)in_sizes; (void)n_in; (void)out_size; (void)ws_size;
  const float* x    = (const float*)d_in[0];
  const float* Wih0 = (const float*)d_in[1];
  const float* Whh0 = (const float*)d_in[2];
  const float* bi0  = (const float*)d_in[3];
  const float* bh0  = (const float*)d_in[4];
  const float* Wih1 = (const float*)d_in[5];
  const float* Whh1 = (const float*)d_in[6];
  const float* bi1  = (const float*)d_in[7];
  const float* bh1  = (const float*)d_in[8];
  const float* Wlin = (const float*)d_in[9];
  const float* blin = (const float*)d_in[10];
  float* out = (float*)d_out;
  char* ws = (char*)d_ws;

  half_t* S0  = (half_t*)(ws + 0);         // 128 x 40960 x 2 = 10 MB
  half_t* S1  = (half_t*)(ws + 10485760);  // 128 x 65536 x 2 = 16 MB
  half_t* SD  = (half_t*)(ws + 27262976);  // 16 MB
  half_t* SY  = (half_t*)(ws + 44040192);  // 512 KB
  half_t* XH  = (half_t*)(ws + 44564480);  // 16 MB
  float*  B0P = (float*)(ws + 61341696);   // 16 KB
  float*  B1P = (float*)(ws + 61358080);   // 16 KB
  float*  BD0P= (float*)(ws + 61374464);   // 17408 B
  int*    CNT = (int*)(ws + 61391872);     // 256 B
  half_t* H0  = (half_t*)(ws + 61392128);  // ring: 320 x 256 KB = 80 MB
  half_t* H1  = (half_t*)(ws + 145278208); // ring: 80 MB -> ends 229,164,288

  // zero barrier counter + slot 0 of each h ring
  hipMemsetAsync(ws + 61391872, 0, 262400, stream);   // CNT + H0 slot 0
  hipMemsetAsync(H1, 0, 262144, stream);              // H1 slot 0

  k_cvt_x<<<4096, 256, 0, stream>>>(x, XH);
  k_bias_simple<<<17, 256, 0, stream>>>(bi0, bh0, bi1, bh1, blin, B0P, B1P, BD0P);
  k_bias_dot<<<1024, 256, 0, stream>>>(Wih0, blin, bi0, bh0, BD0P);
  k_pack32<<<2560, 256, 0, stream>>>(Wih0, 256, Whh0, S0, 40, 0);
  k_pack32<<<4096, 256, 0, stream>>>(Wih1, 1024, Whh1, S1, 64, 0);
  k_pack32<<<4096, 256, 0, stream>>>(nullptr, 1024, Whh0, SD, 64, 1);
  k_pack_y32<<<128, 256, 0, stream>>>(Wlin, SY);
  k_weff<<<dim3(64, 16), 256, 0, stream>>>(Wih0, Wlin, SD);

  k_lstm<<<256, 256, 0, stream>>>(S0, S1, SD, SY, XH, H0, H1,
                                  B0P, B1P, BD0P, out, CNT);
}

// Round 6
// 8669.342 us; speedup vs baseline: 1.1591x; 1.0592x over previous
//
#include <hip/hip_runtime.h>
#include <hip/hip_bf16.h>
#include <cstdint>

// ============================================================================
// 2-layer LSTM prefix + 59-step decode, persistent kernel, round 6.
// Round-6 change (theory: r3/r4/r5 all ~25 us/step regardless of memory
// behavior => the full-grid barrier dominates): NO GLOBAL BARRIER.
// Distributed per-step flag records (one 128B line per super-step):
//   FLG[j].int[g]    (g 0-7)  : # of L0/cell0 blocks in group g that wrote
//                               their H0[j+1] slice   (target 16)
//   FLG[j].int[8+g]  (g 0-7)  : same for H1[j] producers (target 16)
// Consumers gate each 16-kb K-chunk on its group flag (thread 0 batch-polls
// the line with sc1 16B loads; raw s_barrier per chunk, no vmcnt drain ->
// A-load pipeline stays deep). Blocks run independent step loops; the
// write-once h ring (320 slots) makes arbitrary slip safe.
// Everything else (LDS-resident weights, VGPR c-state, sc1 h-stores,
// plain cached h-loads, fragment-linear layouts) is round-5 verbatim.
// ============================================================================

typedef _Float16 half_t;
typedef _Float16 half8 __attribute__((ext_vector_type(8)));
typedef float float4v __attribute__((ext_vector_type(4)));
typedef int int32x4_t __attribute__((ext_vector_type(4)));
typedef float float32x4_t __attribute__((ext_vector_type(4)));

__device__ float32x4_t llvm_amdgcn_raw_buffer_load_fp32x4(
    int32x4_t srsrc, int voffset, int soffset, int aux)
    __asm("llvm.amdgcn.raw.buffer.load.v4f32");

#define AUX_SC1 16  // device scope: bypass L1/L2, served by IF$

union SrdU { int32x4_t v; struct { const void* p; unsigned nr, fl; } s; };
__device__ __forceinline__ int32x4_t make_srd(const void* p) {
  SrdU u; u.s.p = p; u.s.nr = 0xFFFFFFFFu; u.s.fl = 0x00020000u; return u.v;
}

// Read 4 flag ints device-coherently; bit i set iff p[i] >= 16.
__device__ __forceinline__ unsigned poll4(const int* p) {
  union { float32x4_t f; int i[4]; } u;
  u.f = llvm_amdgcn_raw_buffer_load_fp32x4(make_srd(p), 0, 0, AUX_SC1);
  unsigned m = 0;
  if (u.i[0] >= 16) m |= 1u;
  if (u.i[1] >= 16) m |= 2u;
  if (u.i[2] >= 16) m |= 4u;
  if (u.i[3] >= 16) m |= 8u;
  return m;
}

__device__ __forceinline__ void flag_add(int* p) {
  __hip_atomic_fetch_add(p, 1, __ATOMIC_RELAXED, __HIP_MEMORY_SCOPE_AGENT);
}

__device__ __forceinline__ float sigm_(float x) { return 1.0f / (1.0f + __expf(-x)); }
__device__ __forceinline__ float tanh_(float x) {
  float ax = fabsf(x);
  float e = __expf(-2.0f * ax);
  float t = (1.0f - e) / (1.0f + e);
  return x < 0.0f ? -t : t;
}

#define MFMA16(a, b, c) __builtin_amdgcn_mfma_f32_16x16x32_f16(a, b, c, 0, 0, 0)

// [128 x 32] tile GEMM over NCH chunks of 16 kb (128 k). First K0C chunks
// from A0, rest from A1 (both fragment-linear [kb][row 128][8]).
// fA / fB: 8-int group-flag arrays gating the A0 / A1 chunks (nullptr = no
// gate). W: LDS-resident (WLDS) or global stream, layout [kk][lq 4][col 32][8].
template <int NCH, int K0C, bool WLDS>
__device__ __forceinline__ void gemm_f(
    const half_t* __restrict__ A0, const half_t* __restrict__ A1,
    const int* fA, const int* fB, const half_t* W, int tid,
    float4v acc[2][2]) {
  const int l = tid & 63, rg = tid >> 6;
  const int lrow = l & 15, lq = l >> 4;
  const int ro = (rg * 32 + lrow) * 8 + lq * 1024;
  unsigned got = 0;
  if (!fA) got |= (1u << K0C) - 1;
  if (!fB) got |= ~((1u << K0C) - 1);
  if (tid == 0) {
    if (fA) { got |= poll4(fA); got |= poll4(fA + 4) << 4; }
    if (fB) { unsigned m = poll4(fB) | (poll4(fB + 4) << 4); got |= m << K0C; }
  }
#pragma unroll
  for (int c = 0; c < NCH; ++c) {
    if (tid == 0 && !((got >> c) & 1)) {
      do {
        if (c < K0C) {
          const int b = c & ~3;
          got |= poll4(fA + b) << b;
        } else {
          const int cb = (c - K0C) & ~3;
          got |= poll4(fB + cb) << (K0C + cb);
        }
        if (!((got >> c) & 1)) __builtin_amdgcn_s_sleep(2);
      } while (!((got >> c) & 1));
    }
    asm volatile("" ::: "memory");
    __builtin_amdgcn_s_barrier();  // raw: no waitcnt -> loads stay in flight
    asm volatile("" ::: "memory");
#pragma unroll
    for (int k4 = 0; k4 < 4; ++k4) {
      const int kk = c * 4 + k4;
      const int kb = kk * 4;
      const half_t* ap =
          (kb < K0C * 16 ? A0 + (long)kb * 1024
                         : A1 + (long)(kb - K0C * 16) * 1024) + ro;
      half8 a0 = *(const half8*)ap;
      half8 a1 = *(const half8*)(ap + 128);
      const half_t* bp = W + kk * 1024 + lq * 256 + lrow * 8;
      half8 b0 = *(const half8*)bp;
      half8 b1 = *(const half8*)(bp + 128);
      acc[0][0] = MFMA16(a0, b0, acc[0][0]);
      acc[0][1] = MFMA16(a0, b1, acc[0][1]);
      acc[1][0] = MFMA16(a1, b0, acc[1][0]);
      acc[1][1] = MFMA16(a1, b1, acc[1][1]);
    }
  }
}

// Cell epilogue for a [128 x 32] gate tile (8 units x 4 gates per col group).
// c persists in 4 VGPRs; h staged via 2 KB LDS tile, stored sc1 to ring slot.
__device__ __forceinline__ void epi_gates(
    float4v acc[2][2], int tile, const float* __restrict__ biasArr,
    float c[2][2], half_t* hTile, half_t* __restrict__ hDst, int tid) {
  const int l = tid & 63, rg = tid >> 6;
  const int lrow = l & 15, lq = l >> 4, q = l & 3, a = lrow >> 2;
#pragma unroll
  for (int m = 0; m < 2; ++m)
#pragma unroll
    for (int nf = 0; nf < 2; ++nf) {
      const float bias = biasArr[tile * 32 + nf * 16 + lrow];
      float gi = 0.f, gf = 0.f, gg = 0.f, go = 0.f;
#pragma unroll
      for (int r = 0; r < 4; ++r) {
        float x = acc[m][nf][r] + bias;
        float t1 = __shfl_xor(x, 1);
        float t2 = __shfl_xor(x, 2);
        float t3 = __shfl_xor(x, 3);
        if (r == q) {
          gi = (q == 0) ? x : (q == 1 ? t1 : (q == 2 ? t2 : t3));
          gf = (q == 1) ? x : (q == 0 ? t1 : (q == 3 ? t2 : t3));
          gg = (q == 2) ? x : (q == 3 ? t1 : (q == 0 ? t2 : t3));
          go = (q == 3) ? x : (q == 2 ? t1 : (q == 1 ? t2 : t3));
        }
      }
      const int row = rg * 32 + m * 16 + lq * 4 + q;
      const int ju = nf * 4 + a;
      float iv = sigm_(gi), fv = sigm_(gf), gv = tanh_(gg), ov = sigm_(go);
      float cnew = fv * c[m][nf] + iv * gv;
      c[m][nf] = cnew;
      hTile[row * 8 + ju] = (half_t)(ov * tanh_(cnew));
    }
  __syncthreads();
  if (tid < 128) {
    const unsigned long long* s = (const unsigned long long*)(hTile + tid * 8);
    unsigned long long v0 = s[0], v1 = s[1];
    unsigned long long* d = (unsigned long long*)(hDst + tid * 8);
    __hip_atomic_store(d, v0, __ATOMIC_RELAXED, __HIP_MEMORY_SCOPE_AGENT);
    __hip_atomic_store(d + 1, v1, __ATOMIC_RELAXED, __HIP_MEMORY_SCOPE_AGENT);
  }
}

__device__ __forceinline__ void epi_y(
    float4v acc[2][2], int ytile, int i, const float* __restrict__ biasY,
    float* __restrict__ out, int tid) {
  const int l = tid & 63, rg = tid >> 6;
  const int lrow = l & 15, lq = l >> 4;
#pragma unroll
  for (int m = 0; m < 2; ++m)
#pragma unroll
    for (int nf = 0; nf < 2; ++nf) {
      const int d = ytile * 32 + nf * 16 + lrow;
      const float b = biasY[d];
#pragma unroll
      for (int r = 0; r < 4; ++r) {
        const int row = rg * 32 + m * 16 + lq * 4 + r;
        out[(long)row * 15360 + i * 256 + d] = acc[m][nf][r] + b;
      }
    }
}

__device__ __forceinline__ void loadW(const half_t* __restrict__ src,
                                      half_t* dst, int halves, int tid) {
  for (int i = tid * 8; i < halves; i += 2048)
    *(uint4*)(dst + i) = *(const uint4*)(src + i);
}

#define ZACC2 float4v acc[2][2]; { float4v z = {0.f, 0.f, 0.f, 0.f}; \
  acc[0][0] = z; acc[0][1] = z; acc[1][0] = z; acc[1][1] = z; }

__global__ void __launch_bounds__(256, 1) k_lstm(
    const half_t* __restrict__ S0, const half_t* __restrict__ S1,
    const half_t* __restrict__ SD, const half_t* __restrict__ SY,
    const half_t* __restrict__ XH,
    half_t* __restrict__ H0, half_t* __restrict__ H1,
    const float* __restrict__ B0P, const float* __restrict__ B1P,
    const float* __restrict__ BD0P, float* __restrict__ out, int* FLG) {
  __shared__ char smem[133120];  // 128 KB W (persistent) + 2 KB hTile
  half_t* ldsW = (half_t*)smem;
  half_t* hTile = (half_t*)(smem + 131072);
  const int w = blockIdx.x, tid = threadIdx.x;
  float c2[2][2] = {{0.f, 0.f}, {0.f, 0.f}};
#define SLOTP(base, idx) ((base) + (long)(idx) * 131072)

  if (w < 128) {  // ============ L0 prefix + decode cell0 ============
    const int g = w >> 4;
    loadW(S0 + (long)w * 40960, ldsW, 40960, tid);
    __syncthreads();
    for (int s = 0; s < 256; ++s) {
      ZACC2;
      const int* fB = (s >= 1) ? (FLG + (s - 1) * 32) : nullptr;
      gemm_f<10, 2, true>(XH + (long)s * 32768, SLOTP(H0, s),
                          nullptr, fB, ldsW, tid, acc);
      epi_gates(acc, w, B0P, c2, hTile, SLOTP(H0, s + 1) + w * 1024, tid);
      __syncthreads();  // drain sc1 h-stores before flagging
      if (tid == 0) flag_add(FLG + s * 32 + g);
    }
    __syncthreads();
    loadW(SD + (long)w * 65536, ldsW, 65536, tid);  // swap in Weff|Whh0
    __syncthreads();
    for (int i = 0; i < 59; ++i) {
      ZACC2;
      gemm_f<16, 8, true>(SLOTP(H1, 256 + i), SLOTP(H0, 256 + i),
                          FLG + (256 + i) * 32 + 8, FLG + (255 + i) * 32,
                          ldsW, tid, acc);
      epi_gates(acc, w, BD0P, c2, hTile, SLOTP(H0, 257 + i) + w * 1024, tid);
      __syncthreads();
      if (tid == 0) flag_add(FLG + (256 + i) * 32 + g);
    }
  } else {  // ============ L1 prefix + decode cell1 (+ y on 248-255) ========
    const int bw = w - 128, g = bw >> 4;
    loadW(S1 + (long)bw * 65536, ldsW, 65536, tid);
    __syncthreads();
    for (int s = 1; s <= 256; ++s) {
      ZACC2;
      const int* fB = (s >= 2) ? (FLG + (s - 1) * 32 + 8) : nullptr;
      gemm_f<16, 8, true>(SLOTP(H0, s), SLOTP(H1, s - 1),
                          FLG + (s - 1) * 32, fB, ldsW, tid, acc);
      epi_gates(acc, bw, B1P, c2, hTile, SLOTP(H1, s) + bw * 1024, tid);
      __syncthreads();
      if (tid == 0) flag_add(FLG + s * 32 + 8 + g);
    }
    for (int i = 0; i < 59; ++i) {
      ZACC2;
      gemm_f<16, 8, true>(SLOTP(H0, 257 + i), SLOTP(H1, 256 + i),
                          FLG + (256 + i) * 32, FLG + (256 + i) * 32 + 8,
                          ldsW, tid, acc);
      epi_gates(acc, bw, B1P, c2, hTile, SLOTP(H1, 257 + i) + bw * 1024, tid);
      __syncthreads();
      if (tid == 0) flag_add(FLG + (257 + i) * 32 + 8 + g);
      if (w >= 248) {  // y@i off the critical path (flag already raised)
        ZACC2;
        gemm_f<8, 8, false>(SLOTP(H1, 256 + i), (const half_t*)0,
                            FLG + (256 + i) * 32 + 8, nullptr,
                            SY + (long)(w - 248) * 32768, tid, acc);
        epi_y(acc, w - 248, i, BD0P + 4096, out, tid);
      }
    }
    if (w >= 248) {  // final y (step 59) from H1[315]
      ZACC2;
      gemm_f<8, 8, false>(SLOTP(H1, 315), (const half_t*)0,
                          FLG + 315 * 32 + 8, nullptr,
                          SY + (long)(w - 248) * 32768, tid, acc);
      epi_y(acc, w - 248, 59, BD0P + 4096, out, tid);
    }
  }
#undef SLOTP
}

// ======================= setup kernels (round-5 verbatim) ===================

__global__ void k_cvt_x(const float* __restrict__ x, half_t* __restrict__ XH) {
  int idx = blockIdx.x * 256 + threadIdx.x;  // 1,048,576 total
  int t = idx >> 12;
  int kb = (idx >> 7) & 31;
  int r = idx & 127;
  const float* src = x + ((long)((r << 8) + t)) * 256 + kb * 8;
  float4 v0 = *(const float4*)src;
  float4 v1 = *(const float4*)(src + 4);
  half_t tmp[8] = {(half_t)v0.x, (half_t)v0.y, (half_t)v0.z, (half_t)v0.w,
                   (half_t)v1.x, (half_t)v1.y, (half_t)v1.z, (half_t)v1.w};
  *(uint4*)(XH + (long)t * 32768 + kb * 1024 + r * 8) = *(const uint4*)tmp;
}

__global__ void k_pack32(const float* __restrict__ A, int KA,
                         const float* __restrict__ Bsrc,
                         half_t* __restrict__ dst, int KT32, int skipA) {
  int idx = blockIdx.x * 256 + threadIdx.x;
  int nn = idx & 31;
  int lq = (idx >> 5) & 3;
  int t2 = idx >> 7;
  int kk = t2 % KT32;
  int tile = t2 / KT32;
  if (tile >= 128) return;
  int k = kk * 32 + lq * 8;
  int rp = tile * 32 + nn;
  int r = ((rp & 3) << 10) + (rp >> 2);
  const float* src;
  if (k < KA) {
    if (skipA) return;
    src = A + (long)r * KA + k;
  } else {
    src = Bsrc + (long)r * 1024 + (k - KA);
  }
  float4 v0 = *(const float4*)src;
  float4 v1 = *(const float4*)(src + 4);
  half_t tmp[8] = {(half_t)v0.x, (half_t)v0.y, (half_t)v0.z, (half_t)v0.w,
                   (half_t)v1.x, (half_t)v1.y, (half_t)v1.z, (half_t)v1.w};
  *(uint4*)(dst + (long)tile * (KT32 * 1024) + kk * 1024 + lq * 256 + nn * 8) =
      *(const uint4*)tmp;
}

__global__ void k_pack_y32(const float* __restrict__ Wlin,
                           half_t* __restrict__ SY) {
  int idx = blockIdx.x * 256 + threadIdx.x;  // 32768 total
  int nn = idx & 31;
  int lq = (idx >> 5) & 3;
  int kk = (idx >> 7) & 31;
  int tile = idx >> 12;
  int d = tile * 32 + nn;
  int k = kk * 32 + lq * 8;
  const float* src = Wlin + (long)d * 1024 + k;
  float4 v0 = *(const float4*)src;
  float4 v1 = *(const float4*)(src + 4);
  half_t tmp[8] = {(half_t)v0.x, (half_t)v0.y, (half_t)v0.z, (half_t)v0.w,
                   (half_t)v1.x, (half_t)v1.y, (half_t)v1.z, (half_t)v1.w};
  *(uint4*)(SY + (long)tile * 32768 + kk * 1024 + lq * 256 + nn * 8) =
      *(const uint4*)tmp;
}

__global__ void k_bias_simple(const float* bi0, const float* bh0,
                              const float* bi1, const float* bh1,
                              const float* blin, float* b0p, float* b1p,
                              float* bD0p) {
  int rp = blockIdx.x * blockDim.x + threadIdx.x;
  if (rp < 4096) {
    int r = ((rp & 3) << 10) + (rp >> 2);
    b0p[rp] = bi0[r] + bh0[r];
    b1p[rp] = bi1[r] + bh1[r];
  } else if (rp < 4352) {
    bD0p[rp] = blin[rp - 4096];
  }
}

__global__ void k_bias_dot(const float* __restrict__ Wih0,
                           const float* __restrict__ blin,
                           const float* __restrict__ bi0,
                           const float* __restrict__ bh0,
                           float* __restrict__ bD0p) {
  int wv = threadIdx.x >> 6, l = threadIdx.x & 63;
  int r = blockIdx.x * 4 + wv;
  float s = 0.f;
#pragma unroll
  for (int c = 0; c < 4; ++c) s += Wih0[r * 256 + c * 64 + l] * blin[c * 64 + l];
#pragma unroll
  for (int o = 32; o >= 1; o >>= 1) s += __shfl_xor(s, o);
  if (l == 0) {
    int rp = ((r & 1023) << 2) | (r >> 10);
    bD0p[rp] = bi0[r] + bh0[r] + s;
  }
}

__global__ void k_weff(const float* __restrict__ Wih0,
                       const float* __restrict__ Wlin,
                       half_t* __restrict__ SD) {
  __shared__ float At[64][65];
  __shared__ float Bt[64][65];
  const int rt = blockIdx.x, jt = blockIdx.y;
  const int tid = threadIdx.x;
  const int tx = tid & 15, ty = tid >> 4;
  float acc[4][4] = {};
  for (int k0 = 0; k0 < 256; k0 += 64) {
    __syncthreads();
#pragma unroll
    for (int i = 0; i < 16; ++i) {
      int lin = tid + 256 * i;
      int rr = lin >> 6, kk = lin & 63;
      At[rr][kk] = Wih0[(rt * 64 + rr) * 256 + k0 + kk];
      Bt[rr][kk] = Wlin[(k0 + rr) * 1024 + jt * 64 + kk];
    }
    __syncthreads();
    for (int kk = 0; kk < 64; ++kk) {
      float a[4], b[4];
#pragma unroll
      for (int i = 0; i < 4; ++i) a[i] = At[ty * 4 + i][kk];
#pragma unroll
      for (int i = 0; i < 4; ++i) b[i] = Bt[kk][tx * 4 + i];
#pragma unroll
      for (int i = 0; i < 4; ++i)
#pragma unroll
        for (int jx = 0; jx < 4; ++jx) acc[i][jx] += a[i] * b[jx];
    }
  }
#pragma unroll
  for (int i = 0; i < 4; ++i) {
    int r = rt * 64 + ty * 4 + i;
    int rp = ((r & 1023) << 2) | (r >> 10);
    int tile = rp >> 5, nn = rp & 31;
#pragma unroll
    for (int jx = 0; jx < 4; ++jx) {
      int j = jt * 64 + tx * 4 + jx;
      SD[(long)tile * 65536 + (j >> 5) * 1024 + ((j >> 3) & 3) * 256 + nn * 8 +
         (j & 7)] = (half_t)acc[i][jx];
    }
  }
}

// ======================= launch =======================

extern "C" void kernel_launch(void* const* d_in, const int* in_sizes, int n_in,
                              void* d_out, int out_size, void* d_ws, size_t ws_size,
                              hipStream_t stream) {
  (void)in_sizes; (void)n_in; (void)out_size; (void)ws_size;
  const float* x    = (const float*)d_in[0];
  const float* Wih0 = (const float*)d_in[1];
  const float* Whh0 = (const float*)d_in[2];
  const float* bi0  = (const float*)d_in[3];
  const float* bh0  = (const float*)d_in[4];
  const float* Wih1 = (const float*)d_in[5];
  const float* Whh1 = (const float*)d_in[6];
  const float* bi1  = (const float*)d_in[7];
  const float* bh1  = (const float*)d_in[8];
  const float* Wlin = (const float*)d_in[9];
  const float* blin = (const float*)d_in[10];
  float* out = (float*)d_out;
  char* ws = (char*)d_ws;

  half_t* S0  = (half_t*)(ws + 0);         // 128 x 40960 x 2 = 10 MB
  half_t* S1  = (half_t*)(ws + 10485760);  // 128 x 65536 x 2 = 16 MB
  half_t* SD  = (half_t*)(ws + 27262976);  // 16 MB
  half_t* SY  = (half_t*)(ws + 44040192);  // 512 KB
  half_t* XH  = (half_t*)(ws + 44564480);  // 16 MB
  float*  B0P = (float*)(ws + 61341696);   // 16 KB
  float*  B1P = (float*)(ws + 61358080);   // 16 KB
  float*  BD0P= (float*)(ws + 61374464);   // 17408 B
  int*    FLG = (int*)(ws + 61391872);     // 316 x 128 B = 40448 B
  half_t* H0  = (half_t*)(ws + 61432320);  // ring: 320 x 256 KB = 80 MB
  half_t* H1  = (half_t*)(ws + 145318400); // ring: 80 MB -> ends 229,204,480

  // zero flags + H0 slot 0 (contiguous), and H1 slot 0
  hipMemsetAsync(ws + 61391872, 0, 302592, stream);
  hipMemsetAsync(H1, 0, 262144, stream);

  k_cvt_x<<<4096, 256, 0, stream>>>(x, XH);
  k_bias_simple<<<17, 256, 0, stream>>>(bi0, bh0, bi1, bh1, blin, B0P, B1P, BD0P);
  k_bias_dot<<<1024, 256, 0, stream>>>(Wih0, blin, bi0, bh0, BD0P);
  k_pack32<<<2560, 256, 0, stream>>>(Wih0, 256, Whh0, S0, 40, 0);
  k_pack32<<<4096, 256, 0, stream>>>(Wih1, 1024, Whh1, S1, 64, 0);
  k_pack32<<<4096, 256, 0, stream>>>(nullptr, 1024, Whh0, SD, 64, 1);
  k_pack_y32<<<128, 256, 0, stream>>>(Wlin, SY);
  k_weff<<<dim3(64, 16), 256, 0, stream>>>(Wih0, Wlin, SD);

  k_lstm<<<256, 256, 0, stream>>>(S0, S1, SD, SY, XH, H0, H1,
                                  B0P, B1P, BD0P, out, FLG);
}